// Round 8
// baseline (549.692 us; speedup 1.0000x reference)
//
#include <hip/hip_runtime.h>
#include <stdint.h>
#include <stddef.h>

typedef __attribute__((ext_vector_type(8))) short short8;
typedef __attribute__((ext_vector_type(16))) float f32x16;

#define CI 128
#define CO 128
#define SP 32768          // 32*32*32
#define BATCH 8
#define STYLED 512
#define KV 3456           // CI*27

typedef __attribute__((address_space(1))) const void gvoid_t;
typedef __attribute__((address_space(3))) void lvoid_t;
__device__ __forceinline__ void gload16(const void* g, void* l) {
    __builtin_amdgcn_global_load_lds((gvoid_t*)g, (lvoid_t*)l, 16, 0, 0);
}

__device__ __forceinline__ short f2bf(float f) {
    uint32_t u = __builtin_bit_cast(uint32_t, f);
    u = (u + 0x7FFFu + ((u >> 16) & 1u)) >> 16;
    return (short)(u & 0xFFFFu);
}

// style_m[b][i] = 1 + affine_b[i] + sum_d s[b][d]*affine_w[i][d]; block 0 zeros zp
__global__ void k_style(const float* __restrict__ s, const float* __restrict__ aw,
                        const float* __restrict__ ab, float* __restrict__ m,
                        float* __restrict__ zp) {
    __shared__ float ssh[STYLED];
    int b = blockIdx.x;
    int i = threadIdx.x;  // 128 threads
    if (b == 0 && i < 64) zp[i] = 0.f;   // 256B zeropage
    for (int r = 0; r < STYLED / 128; ++r) ssh[r * 128 + i] = s[b * STYLED + r * 128 + i];
    __syncthreads();
    float acc = ab[i] + 1.0f;
    const float4* awr = (const float4*)(aw + (size_t)i * STYLED);
    for (int d4 = 0; d4 < STYLED / 4; ++d4) {
        float4 v = awr[d4];
        acc += v.x * ssh[d4 * 4] + v.y * ssh[d4 * 4 + 1] + v.z * ssh[d4 * 4 + 2] + v.w * ssh[d4 * 4 + 3];
    }
    m[b * CI + i] = acc;
}

// wmodT: per (b, kk=c32*27+tap) an 8KB LDS-image, 256B-packed rows with XOR slots:
// logical (o, q=ci granule) at granule index (o>>2)*16 + (((o&3)*4+q)^((o>>2)&7))
__global__ void k_wmod(const float* __restrict__ w, const float* __restrict__ m,
                       short* __restrict__ wt) {
    int b = blockIdx.x >> 7;
    int o = blockIdx.x & 127;
    int lane = threadIdx.x;   // 64 threads
    const float* wrow = w + (size_t)o * KV;
    const float* mrow = m + b * CI;
    float sum = 0.f;
    for (int e = lane; e < KV; e += 64) {
        int i = e / 27;
        float v = wrow[e] * mrow[i];
        sum += v * v;
    }
    #pragma unroll
    for (int off = 32; off >= 1; off >>= 1) sum += __shfl_xor(sum, off);
    float scale = 1.0f / sqrtf(sum + 1e-8f);
    int row4 = o >> 2;
    int sbase = (o & 3) << 2;
    for (int e = lane; e < KV; e += 64) {
        int i = e / 27;
        int k = e - i * 27;
        float v = wrow[e] * mrow[i] * scale;
        int kk = (i >> 5) * 27 + k;          // ci32 chunk * 27 + tap
        int il = i & 31, q = il >> 3, rr = il & 7;
        int slot = (sbase | q) ^ (row4 & 7);
        wt[(((size_t)(b * 108 + kk)) * 512 + row4 * 16 + slot) * 8 + rr] = f2bf(v);
    }
}

// xT[b][sp][ci] bf16 from x[b][ci][z][y][w] f32. Thread = 2 sp, 32 ch (float2 loads).
__global__ void k_xt(const float* __restrict__ x, short* __restrict__ xt) {
    int bid = blockIdx.x;              // 2048 = 8b * 4c * 64spb
    int b = bid >> 8, c = (bid >> 6) & 3, spb = bid & 63;
    int sp = spb * 512 + threadIdx.x * 2;
    const float* src = x + ((size_t)(b * CI + c * 32)) * SP + sp;
    float2 f[32];
    #pragma unroll
    for (int ch = 0; ch < 32; ++ch) f[ch] = *(const float2*)(src + (size_t)ch * SP);
    short8 v0[4], v1[4];
    #pragma unroll
    for (int q = 0; q < 4; ++q)
        #pragma unroll
        for (int j = 0; j < 8; ++j) {
            v0[q][j] = f2bf(f[q * 8 + j].x);
            v1[q][j] = f2bf(f[q * 8 + j].y);
        }
    short* d0 = xt + (size_t)(b * SP + sp) * CI + c * 32;
    #pragma unroll
    for (int q = 0; q < 4; ++q) *(short8*)(d0 + q * 8) = v0[q];
    #pragma unroll
    for (int q = 0; q < 4; ++q) *(short8*)(d0 + CI + q * 8) = v1[q];
}

// Implicit-GEMM conv. Block = 8 waves (512 thr), tile 128co x 512sp (4z*4y*32w),
// wave grid 2M x 4N, wave tile 64x128, mfma_f32_32x32x16. LDS in 256B-packed
// XOR-slot layout (2-way max bank aliasing for the 32-row x 16B fragment reads).
// Ring-6 weight tap-images; 2-tap phases, counted vmcnt(2); vmcnt(0) only at
// chunk tails. 128KB LDS, 1 block/CU, 2 waves/SIMD.
__launch_bounds__(512, 2)
__global__ void k_conv(const short* __restrict__ xt, const short* __restrict__ wt,
                       const float* __restrict__ bias, float* __restrict__ out,
                       const short* __restrict__ zp) {
    __shared__ short lds_x[40960];     // 81920 B: 320 row4-lines (1224 halo rows + pad)
    __shared__ short lds_w[24576];     // 49152 B: ring of 6 tap images (8KB each)

    int bid = blockIdx.x;
    int b = bid & 7;                 // sample -> XCD affinity
    int s = bid >> 3;                // 0..63
    int z0 = (s & 7) * 4, y0 = (s >> 3) * 4;
    int tid = threadIdx.x, lane = tid & 63, wid = tid >> 6;
    int wm = wid >> 2;               // 0..1 : co half (64)
    int wn = wid & 3;                // 0..3 : z within tile
    int l31 = lane & 31, g5 = lane >> 5;

    const char* xb = (const char*)(xt + (size_t)b * SP * CI);
    const char* wb = (const char*)(wt + (size_t)b * 108 * 4096);

    // hoisted x-staging source offsets: LDS linear granule -> inverse-permuted global addr
    int xoff[10];
    #pragma unroll
    for (int j = 0; j < 10; ++j) {
        int Gl = tid + 512 * j;
        int row4 = Gl >> 4, slot = Gl & 15;
        int sl = slot ^ (row4 & 7);
        int r = row4 * 4 + (sl >> 2), q = sl & 3;
        int zh = r / 204, r2 = r - zh * 204;
        int yh = r2 / 34, wh = r2 - yh * 34;
        int zz = z0 + zh - 1, yy = y0 + yh - 1, ww = wh - 1;
        bool ok = (r < 1224) && ((unsigned)zz < 32u) && ((unsigned)yy < 32u) && ((unsigned)ww < 32u);
        xoff[j] = ok ? ((zz * 1024 + yy * 32 + ww) * 256 + q * 16) : -1;
    }

    // hoisted af image-offsets per (mf, ks)
    int afoff[2][2];
    #pragma unroll
    for (int mf = 0; mf < 2; ++mf)
        #pragma unroll
        for (int ks = 0; ks < 2; ++ks) {
            int o = wm * 64 + mf * 32 + l31;
            int q = ks * 2 + g5;
            int o4 = o >> 2;
            int sl = (((o & 3) << 2) | q) ^ (o4 & 7);
            afoff[mf][ks] = o4 * 256 + sl * 16;
        }

    f32x16 acc[2][4];
    #pragma unroll
    for (int mf = 0; mf < 2; ++mf)
        #pragma unroll
        for (int nf = 0; nf < 4; ++nf)
            #pragma unroll
            for (int e = 0; e < 16; ++e) acc[mf][nf][e] = 0.f;

    #pragma unroll 1
    for (int c = 0; c < 4; ++c) {
        int kk0 = c * 27;
        __builtin_amdgcn_s_barrier();        // prior chunk's lds_x readers done
        asm volatile("" ::: "memory");
        // stage x halo (10 gloads/thread, inverse-permuted sources)
        #pragma unroll
        for (int j = 0; j < 10; ++j) {
            const char* src = (xoff[j] >= 0) ? (xb + xoff[j] + c * 64) : (const char*)zp;
            gload16(src, (void*)((char*)lds_x + wid * 1024 + j * 8192));
        }
        // stage taps 0..3 (1 gload/thread each; image already permuted)
        #pragma unroll
        for (int t = 0; t < 4; ++t)
            gload16(wb + (size_t)(kk0 + t) * 8192 + wid * 1024 + lane * 16,
                    (void*)((char*)lds_w + ((kk0 + t) % 6) * 8192 + wid * 1024));
        asm volatile("s_waitcnt vmcnt(2)" ::: "memory");  // x + taps0,1 landed
        __builtin_amdgcn_s_barrier();
        asm volatile("" ::: "memory");

        #pragma unroll
        for (int p = 0; p < 12; ++p) {
            // stage taps 2p+4, 2p+5 (ring slot freed at last barrier)
            #pragma unroll
            for (int dt = 4; dt < 6; ++dt) {
                int t = 2 * p + dt;
                if (t < 27)
                    gload16(wb + (size_t)(kk0 + t) * 8192 + wid * 1024 + lane * 16,
                            (void*)((char*)lds_w + ((kk0 + t) % 6) * 8192 + wid * 1024));
            }
            // compute taps 2p, 2p+1
            #pragma unroll
            for (int dt = 0; dt < 2; ++dt) {
                int tap = 2 * p + dt;
                int kd = tap / 9, r9 = tap - kd * 9;
                int kh = r9 / 3, kw = r9 - kh * 3;
                const char* wimg = (const char*)lds_w + ((kk0 + tap) % 6) * 8192;
                int Hb = (wn + kd) * 204 + kh * 34 + kw + l31;
                #pragma unroll
                for (int ks = 0; ks < 2; ++ks) {
                    int q = ks * 2 + g5;
                    short8 af0 = *(const short8*)(wimg + afoff[0][ks]);
                    short8 af1 = *(const short8*)(wimg + afoff[1][ks]);
                    short8 bf[4];
                    #pragma unroll
                    for (int nf = 0; nf < 4; ++nf) {
                        int h = Hb + nf * 34;
                        int h4 = h >> 2;
                        int sl = (((h & 3) << 2) | q) ^ (h4 & 7);
                        bf[nf] = *(const short8*)((const char*)lds_x + h4 * 256 + sl * 16);
                    }
                    __builtin_amdgcn_s_setprio(1);
                    #pragma unroll
                    for (int nf = 0; nf < 4; ++nf) {
                        acc[0][nf] = __builtin_amdgcn_mfma_f32_32x32x16_bf16(af0, bf[nf], acc[0][nf], 0, 0, 0);
                        acc[1][nf] = __builtin_amdgcn_mfma_f32_32x32x16_bf16(af1, bf[nf], acc[1][nf], 0, 0, 0);
                    }
                    __builtin_amdgcn_s_setprio(0);
                }
            }
            if (p < 11) asm volatile("s_waitcnt vmcnt(2)" ::: "memory");
            else        asm volatile("s_waitcnt vmcnt(0)" ::: "memory");
            __builtin_amdgcn_s_barrier();
            asm volatile("" ::: "memory");
        }
        // tail: taps 24,25,26 (all landed; no staging in flight)
        #pragma unroll
        for (int tap = 24; tap < 27; ++tap) {
            int kd = tap / 9, r9 = tap - kd * 9;
            int kh = r9 / 3, kw = r9 - kh * 3;
            const char* wimg = (const char*)lds_w + ((kk0 + tap) % 6) * 8192;
            int Hb = (wn + kd) * 204 + kh * 34 + kw + l31;
            #pragma unroll
            for (int ks = 0; ks < 2; ++ks) {
                int q = ks * 2 + g5;
                short8 af0 = *(const short8*)(wimg + afoff[0][ks]);
                short8 af1 = *(const short8*)(wimg + afoff[1][ks]);
                short8 bf[4];
                #pragma unroll
                for (int nf = 0; nf < 4; ++nf) {
                    int h = Hb + nf * 34;
                    int h4 = h >> 2;
                    int sl = (((h & 3) << 2) | q) ^ (h4 & 7);
                    bf[nf] = *(const short8*)((const char*)lds_x + h4 * 256 + sl * 16);
                }
                __builtin_amdgcn_s_setprio(1);
                #pragma unroll
                for (int nf = 0; nf < 4; ++nf) {
                    acc[0][nf] = __builtin_amdgcn_mfma_f32_32x32x16_bf16(af0, bf[nf], acc[0][nf], 0, 0, 0);
                    acc[1][nf] = __builtin_amdgcn_mfma_f32_32x32x16_bf16(af1, bf[nf], acc[1][nf], 0, 0, 0);
                }
                __builtin_amdgcn_s_setprio(0);
            }
        }
    }

    // epilogue: D col=lane&31 (w), row=(j&3)+8*(j>>2)+4*(lane>>5) (co)  [R4/R6-verified]
    size_t ob = (size_t)b * CO * SP;
    #pragma unroll
    for (int mf = 0; mf < 2; ++mf)
        #pragma unroll
        for (int nf = 0; nf < 4; ++nf) {
            int z = z0 + wn, y = y0 + nf;
            size_t base = ob + (size_t)z * 1024 + y * 32 + l31;
            #pragma unroll
            for (int j = 0; j < 16; ++j) {
                int co = wm * 64 + mf * 32 + (j & 3) + 8 * (j >> 2) + 4 * g5;
                out[base + (size_t)co * SP] = acc[mf][nf][j] + bias[co];
            }
        }
}

extern "C" void kernel_launch(void* const* d_in, const int* in_sizes, int n_in,
                              void* d_out, int out_size, void* d_ws, size_t ws_size,
                              hipStream_t stream) {
    const float* x  = (const float*)d_in[0];
    const float* s  = (const float*)d_in[1];
    const float* w  = (const float*)d_in[2];
    const float* bb = (const float*)d_in[3];
    const float* aw = (const float*)d_in[4];
    const float* ab = (const float*)d_in[5];
    float* out = (float*)d_out;

    // workspace layout
    float* style_m = (float*)d_ws;                                      // 4 KB
    short* wmodT   = (short*)((char*)d_ws + 4096);                      // 8*108*8192 B = 7,077,888 B
    short* xT      = (short*)((char*)d_ws + 4096 + 7077888);            // 67,108,864 B
    float* zpage   = (float*)((char*)d_ws + 4096 + 7077888 + 67108864); // 256 B zeros

    k_style<<<BATCH, 128, 0, stream>>>(s, aw, ab, style_m, zpage);
    k_wmod<<<BATCH * CO, 64, 0, stream>>>(w, style_m, wmodT);
    k_xt<<<BATCH * 4 * 64, 256, 0, stream>>>(x, xT);
    k_conv<<<BATCH * 64, 512, 0, stream>>>(xT, wmodT, bb, out, (const short*)zpage);
}

// Round 9
// 311.326 us; speedup vs baseline: 1.7656x; 1.7656x over previous
//
#include <hip/hip_runtime.h>
#include <stdint.h>
#include <stddef.h>

typedef __attribute__((ext_vector_type(8))) short short8;
typedef __attribute__((ext_vector_type(16))) float f32x16;

#define CI 128
#define CO 128
#define SP 32768          // 32*32*32
#define BATCH 8
#define STYLED 512
#define KV 3456           // CI*27

typedef __attribute__((address_space(1))) const void gvoid_t;
typedef __attribute__((address_space(3))) void lvoid_t;
__device__ __forceinline__ void gload16(const void* g, void* l) {
    __builtin_amdgcn_global_load_lds((gvoid_t*)g, (lvoid_t*)l, 16, 0, 0);
}

__device__ __forceinline__ short f2bf(float f) {
    uint32_t u = __builtin_bit_cast(uint32_t, f);
    u = (u + 0x7FFFu + ((u >> 16) & 1u)) >> 16;
    return (short)(u & 0xFFFFu);
}

// style_m[b][i] = 1 + affine_b[i] + sum_d s[b][d]*affine_w[i][d]; block 0 zeros zp
__global__ void k_style(const float* __restrict__ s, const float* __restrict__ aw,
                        const float* __restrict__ ab, float* __restrict__ m,
                        float* __restrict__ zp) {
    __shared__ float ssh[STYLED];
    int b = blockIdx.x;
    int i = threadIdx.x;  // 128 threads
    if (b == 0 && i < 64) zp[i] = 0.f;   // 256B zeropage
    for (int r = 0; r < STYLED / 128; ++r) ssh[r * 128 + i] = s[b * STYLED + r * 128 + i];
    __syncthreads();
    float acc = ab[i] + 1.0f;
    const float4* awr = (const float4*)(aw + (size_t)i * STYLED);
    for (int d4 = 0; d4 < STYLED / 4; ++d4) {
        float4 v = awr[d4];
        acc += v.x * ssh[d4 * 4] + v.y * ssh[d4 * 4 + 1] + v.z * ssh[d4 * 4 + 2] + v.w * ssh[d4 * 4 + 3];
    }
    m[b * CI + i] = acc;
}

// wmodT: per (b, kk=c32*27+tap) an 8KB LDS-image, 256B-packed rows with XOR slots:
// logical (o, q=ci granule) at granule (o>>2)*16 + (((o&3)*4+q)^((o>>2)&7))
__global__ void k_wmod(const float* __restrict__ w, const float* __restrict__ m,
                       short* __restrict__ wt) {
    int b = blockIdx.x >> 7;
    int o = blockIdx.x & 127;
    int lane = threadIdx.x;   // 64 threads
    const float* wrow = w + (size_t)o * KV;
    const float* mrow = m + b * CI;
    float sum = 0.f;
    for (int e = lane; e < KV; e += 64) {
        int i = e / 27;
        float v = wrow[e] * mrow[i];
        sum += v * v;
    }
    #pragma unroll
    for (int off = 32; off >= 1; off >>= 1) sum += __shfl_xor(sum, off);
    float scale = 1.0f / sqrtf(sum + 1e-8f);
    int row4 = o >> 2;
    int sbase = (o & 3) << 2;
    for (int e = lane; e < KV; e += 64) {
        int i = e / 27;
        int k = e - i * 27;
        float v = wrow[e] * mrow[i] * scale;
        int kk = (i >> 5) * 27 + k;          // ci32 chunk * 27 + tap
        int il = i & 31, q = il >> 3, rr = il & 7;
        int slot = (sbase | q) ^ (row4 & 7);
        wt[(((size_t)(b * 108 + kk)) * 512 + row4 * 16 + slot) * 8 + rr] = f2bf(v);
    }
}

// xT[b][sp][ci] bf16 from x[b][ci][z][y][w] f32. Thread = 2 sp, 32 ch (float2 loads).
__global__ void k_xt(const float* __restrict__ x, short* __restrict__ xt) {
    int bid = blockIdx.x;              // 2048 = 8b * 4c * 64spb
    int b = bid >> 8, c = (bid >> 6) & 3, spb = bid & 63;
    int sp = spb * 512 + threadIdx.x * 2;
    const float* src = x + ((size_t)(b * CI + c * 32)) * SP + sp;
    float2 f[32];
    #pragma unroll
    for (int ch = 0; ch < 32; ++ch) f[ch] = *(const float2*)(src + (size_t)ch * SP);
    short8 v0[4], v1[4];
    #pragma unroll
    for (int q = 0; q < 4; ++q)
        #pragma unroll
        for (int j = 0; j < 8; ++j) {
            v0[q][j] = f2bf(f[q * 8 + j].x);
            v1[q][j] = f2bf(f[q * 8 + j].y);
        }
    short* d0 = xt + (size_t)(b * SP + sp) * CI + c * 32;
    #pragma unroll
    for (int q = 0; q < 4; ++q) *(short8*)(d0 + q * 8) = v0[q];
    #pragma unroll
    for (int q = 0; q < 4; ++q) *(short8*)(d0 + CI + q * 8) = v1[q];
}

// Implicit-GEMM conv = R6 schedule + 256B-packed XOR-slot LDS layout.
// Block = 8 waves (512 thr), tile 128co x 512sp (4z*4y*32w), wave grid 2Mx4N,
// wave tile 64x128, mfma_f32_32x32x16. Ring-9 weight tap-images staged 2 phases
// ahead (3-tap phases, counted vmcnt(3)); x halo restaged per ci32 chunk.
__launch_bounds__(512, 2)
__global__ void k_conv(const short* __restrict__ xt, const short* __restrict__ wt,
                       const float* __restrict__ bias, float* __restrict__ out,
                       const short* __restrict__ zp) {
    __shared__ short lds_x[39168];   // 78,336 B: 1224 halo rows packed 4-per-256B line
    __shared__ short lds_w[36864];   // 73,728 B: ring of 9 tap images (8KB each)

    int bid = blockIdx.x;
    int b = bid & 7;                 // sample -> XCD affinity
    int s = bid >> 3;                // 0..63
    int z0 = (s & 7) * 4, y0 = (s >> 3) * 4;
    int tid = threadIdx.x, lane = tid & 63, wid = tid >> 6;
    int wm = wid >> 2;               // 0..1 : co half (64)
    int wn = wid & 3;                // 0..3 : z within tile
    int l31 = lane & 31, g5 = lane >> 5;

    const char* xb = (const char*)(xt + (size_t)b * SP * CI);
    const char* wb = (const char*)(wt + (size_t)b * 108 * 4096);

    // hoisted x-staging sources: linear LDS granule Gl -> inverse-permuted global offset
    int xoff[10];
    #pragma unroll
    for (int j = 0; j < 10; ++j) {
        int Gl = tid + 512 * j;
        int row4 = Gl >> 4;
        int sl = (Gl & 15) ^ (row4 & 7);
        int r = row4 * 4 + (sl >> 2), q = sl & 3;
        int zh = r / 204, r2 = r - zh * 204;
        int yh = r2 / 34, wh = r2 - yh * 34;
        int zz = z0 + zh - 1, yy = y0 + yh - 1, ww = wh - 1;
        bool ok = (Gl < 4896) && ((unsigned)zz < 32u) && ((unsigned)yy < 32u) && ((unsigned)ww < 32u);
        xoff[j] = ok ? ((zz * 1024 + yy * 32 + ww) * 256 + q * 16) : -1;
    }

    f32x16 acc[2][4];
    #pragma unroll
    for (int mf = 0; mf < 2; ++mf)
        #pragma unroll
        for (int nf = 0; nf < 4; ++nf)
            #pragma unroll
            for (int e = 0; e < 16; ++e) acc[mf][nf][e] = 0.f;

    // prologue: stage weight images kk=0..5 (1 granule/thread each)
    #pragma unroll
    for (int t = 0; t < 6; ++t)
        gload16(wb + (size_t)t * 8192 + tid * 16,
                (void*)((char*)lds_w + t * 8192 + wid * 1024 + (lane << 4)));

    #pragma unroll 1
    for (int c = 0; c < 4; ++c) {
        // stage x halo for this ci32 chunk (prior readers retired at last barrier)
        #pragma unroll
        for (int j = 0; j < 10; ++j) {
            if (tid + 512 * j < 4896) {
                const char* src = (xoff[j] >= 0) ? (xb + xoff[j] + c * 64) : (const char*)zp;
                gload16(src, (void*)((char*)lds_x + wid * 1024 + j * 8192));
            }
        }
        asm volatile("s_waitcnt vmcnt(0)" ::: "memory");   // chunk boundary: full drain
        __builtin_amdgcn_s_barrier();
        asm volatile("" ::: "memory");

        int kk0 = c * 27;
        #pragma unroll 1
        for (int ph = 0; ph < 9; ++ph) {
            // stage phase ph+2's 3 taps (ring slot's prior reader was phase ph-1)
            #pragma unroll
            for (int q = 0; q < 3; ++q) {
                int kt = kk0 + ph * 3 + 6 + q;
                int buf = kt % 9;
                int ksrc = (kt >= 108) ? kt - 108 : kt;    // dummy wrap at tail
                gload16(wb + (size_t)ksrc * 8192 + tid * 16,
                        (void*)((char*)lds_w + buf * 8192 + wid * 1024 + (lane << 4)));
            }
            // compute 3 taps
            #pragma unroll
            for (int t = 0; t < 3; ++t) {
                int tap = ph * 3 + t;
                int kd = tap / 9, r9 = tap - kd * 9;
                int kh = r9 / 3, kw = r9 - kh * 3;
                const char* wimg = (const char*)lds_w + ((kk0 + tap) % 9) * 8192;
                int hb = (wn + kd) * 204 + kh * 34 + l31 + kw;

                #pragma unroll
                for (int ks = 0; ks < 2; ++ks) {
                    int q = ks * 2 + g5;
                    short8 af[2];
                    #pragma unroll
                    for (int mf = 0; mf < 2; ++mf) {
                        int o = wm * 64 + mf * 32 + l31;
                        int o4 = o >> 2;
                        int sl = (((o & 3) << 2) | q) ^ (o4 & 7);
                        af[mf] = *(const short8*)(wimg + o4 * 256 + sl * 16);
                    }
                    short8 bf[4];
                    #pragma unroll
                    for (int nf = 0; nf < 4; ++nf) {
                        int h = hb + nf * 34;
                        int h4 = h >> 2;
                        int sl = (((h & 3) << 2) | q) ^ (h4 & 7);
                        bf[nf] = *(const short8*)((const char*)lds_x + h4 * 256 + sl * 16);
                    }
                    __builtin_amdgcn_s_setprio(1);
                    #pragma unroll
                    for (int nf = 0; nf < 4; ++nf) {
                        acc[0][nf] = __builtin_amdgcn_mfma_f32_32x32x16_bf16(af[0], bf[nf], acc[0][nf], 0, 0, 0);
                        acc[1][nf] = __builtin_amdgcn_mfma_f32_32x32x16_bf16(af[1], bf[nf], acc[1][nf], 0, 0, 0);
                    }
                    __builtin_amdgcn_s_setprio(0);
                }
            }
            asm volatile("s_waitcnt vmcnt(3)" ::: "memory");  // counted: phase ph+1's taps landed
            __builtin_amdgcn_s_barrier();
            asm volatile("" ::: "memory");
        }
    }

    // epilogue: D col=lane&31 (w), row=(j&3)+8*(j>>2)+4*(lane>>5) (co)  [R4/R6-verified]
    size_t ob = (size_t)b * CO * SP;
    #pragma unroll
    for (int mf = 0; mf < 2; ++mf)
        #pragma unroll
        for (int nf = 0; nf < 4; ++nf) {
            int z = z0 + wn, y = y0 + nf;
            size_t base = ob + (size_t)z * 1024 + y * 32 + l31;
            #pragma unroll
            for (int j = 0; j < 16; ++j) {
                int co = wm * 64 + mf * 32 + (j & 3) + 8 * (j >> 2) + 4 * g5;
                out[base + (size_t)co * SP] = acc[mf][nf][j] + bias[co];
            }
        }
}

extern "C" void kernel_launch(void* const* d_in, const int* in_sizes, int n_in,
                              void* d_out, int out_size, void* d_ws, size_t ws_size,
                              hipStream_t stream) {
    const float* x  = (const float*)d_in[0];
    const float* s  = (const float*)d_in[1];
    const float* w  = (const float*)d_in[2];
    const float* bb = (const float*)d_in[3];
    const float* aw = (const float*)d_in[4];
    const float* ab = (const float*)d_in[5];
    float* out = (float*)d_out;

    // workspace layout
    float* style_m = (float*)d_ws;                                      // 4 KB
    short* wmodT   = (short*)((char*)d_ws + 4096);                      // 8*108*8192 B = 7,077,888 B
    short* xT      = (short*)((char*)d_ws + 4096 + 7077888);            // 67,108,864 B
    float* zpage   = (float*)((char*)d_ws + 4096 + 7077888 + 67108864); // 256 B zeros

    k_style<<<BATCH, 128, 0, stream>>>(s, aw, ab, style_m, zpage);
    k_wmod<<<BATCH * CO, 64, 0, stream>>>(w, style_m, wmodT);
    k_xt<<<BATCH * 4 * 64, 256, 0, stream>>>(x, xT);
    k_conv<<<BATCH * 64, 512, 0, stream>>>(xT, wmodT, bb, out, (const short*)zpage);
}